// Round 18
// baseline (467.774 us; speedup 1.0000x reference)
//
#include <hip/hip_runtime.h>
#include <hip/hip_bf16.h>
#include <cstdint>
#include <type_traits>

#define GLOBAL_AS __attribute__((address_space(1)))
#define LDS_AS    __attribute__((address_space(3)))

typedef short bf16x8 __attribute__((ext_vector_type(8)));
typedef short short8_t __attribute__((ext_vector_type(8)));
typedef float f32x16 __attribute__((ext_vector_type(16)));

static constexpr int E_DIM = 1024;
static constexpr int HD = 64;
static constexpr int QKV_STRIDE = 3072;
static constexpr int KDIM = 1024;        // K for both GEMMs
static constexpr int NTK  = KDIM / 64;   // 16 K-tiles
static constexpr int NIT  = NTK / 2;     // 8 iterations (2 K-tiles each)

__device__ __forceinline__ float b2f(short s) {
    union { unsigned u; float f; } x;
    x.u = ((unsigned)(unsigned short)s) << 16;
    return x.f;
}
__device__ __forceinline__ short f2b(float f) {
    union { float f; unsigned u; } x; x.f = f;
    unsigned r = x.u + 0x7FFF + ((x.u >> 16) & 1);
    return (short)(r >> 16);
}

// ---- fused prep: x->bf16, Wq/Wk/Wv->Wqkvb, Wo->Wob, bias concat ----
__global__ __launch_bounds__(256) void k_prep(
    const float* __restrict__ x,
    const float* __restrict__ Wq, const float* __restrict__ Wk,
    const float* __restrict__ Wv, const float* __restrict__ Wo,
    const float* __restrict__ bq, const float* __restrict__ bk,
    const float* __restrict__ bv,
    short* __restrict__ xb, short* __restrict__ Wqkvb, short* __restrict__ Wob,
    float* __restrict__ bqkv, int n4x, int n4w)
{
    int i = blockIdx.x * 256 + threadIdx.x;
    const float* src;
    short* dst;
    int j;
    if (i < n4x)                       { src = x;  dst = xb;                  j = i; }
    else if (i < n4x + n4w)            { src = Wq; dst = Wqkvb;               j = i - n4x; }
    else if (i < n4x + 2 * n4w)        { src = Wk; dst = Wqkvb + 4 * n4w;     j = i - n4x - n4w; }
    else if (i < n4x + 3 * n4w)        { src = Wv; dst = Wqkvb + 8 * n4w;     j = i - n4x - 2 * n4w; }
    else if (i < n4x + 4 * n4w)        { src = Wo; dst = Wob;                 j = i - n4x - 3 * n4w; }
    else {
        int b = i - (n4x + 4 * n4w);
        if (b < 768) {
            #pragma unroll
            for (int e = 0; e < 4; ++e) {
                int idx = b * 4 + e;
                float v = (idx < 1024) ? bq[idx] : (idx < 2048 ? bk[idx - 1024] : bv[idx - 2048]);
                bqkv[idx] = v;
            }
        }
        return;
    }
    float4 v = reinterpret_cast<const float4*>(src)[j];
    short4 o;
    o.x = f2b(v.x); o.y = f2b(v.y); o.z = f2b(v.z); o.w = f2b(v.w);
    reinterpret_cast<short4*>(dst)[j] = o;
}

// ==== 256x256 bf16 GEMM — 32x32x16 MFMA + SLOT-MAJOR LDS (conflict-free) ====
// R17 schedule byte-identical (passed; protocol proven). Only the LDS layout
// changes: each 16 KiB half-region is [slot 0..7][row 0..127] (slot = 16B
// k-chunk). Staging chunk c -> (slot=c>>7, row=c&127); LDS dest stays c*16B
// linear (global_load_lds requirement); the permutation rides on the SOURCE
// address (rule #21 mechanism). Reads: 32 lanes @ fixed slot, rows +0..31 ->
// 512B contiguous -> all 32 banks once -> ZERO conflicts by construction
// (R17's row-major + XOR was structurally 4-way for 32-row column reads).
// Protocol (R17-proven): 8 phases/iter; stages p0:A0(O) p1:A1(O) p2:B0(E2)
// p3:B1(E2) p4:A0(E2) p5:A1(E2) p6:B0(O2) p7:B1(O2); vmcnt(2) at p2/p6 ends
// retires exactly the tile read after the NEXT barrier ({wait->BAR->read}).
// A/B frag: row/col = lane&31, k = (lane>>5)*8+e; C/D: col=lane&31,
// row=(r&3)+8*(r>>2)+4*(lane>>5) [verified by R17 pass + m74/m101].
template <typename OutT>
__global__ __launch_bounds__(512, 2) void k_gemm256(
    const short* __restrict__ A,    // [M][KDIM]
    const short* __restrict__ Bm,   // [N][KDIM]
    const float* __restrict__ bias, // [N]
    OutT* __restrict__ C,           // [M][N]
    int NT_N, int N)
{
    __shared__ short lds[65536];   // [buf]*32768 + [mat]*16384 + [half]*8192

    const int tid  = threadIdx.x;
    const int lane = tid & 63;
    const int wv   = tid >> 6;
    const int wr   = wv >> 2;       // 0..1 M half (128 rows)
    const int wc   = wv & 3;        // 0..3 N quarter (64 cols)
    const int arow = lane & 31;     // row/col within a 32-block
    const int kgrp = lane >> 5;     // k-group: k = kgrp*8 + e

    // bijective XCD swizzle (grid%8==0), n-fastest (neighbors share A-panel)
    const int nwg = gridDim.x, nper = nwg >> 3, bid = blockIdx.x;
    const int swz = (bid & 7) * nper + (bid >> 3);
    const int m0  = (swz / NT_N) * 256;
    const int n0  = (swz % NT_N) * 256;

    // read bases (shorts, within buf): A half = wr; B half = wc>>1, plus
    // 64-row offset (wc&1) inside the half (slot-major: row offset *8).
    const int ArdBase = wr * 8192;
    const int BrdBase = 16384 + (wc >> 1) * 8192 + (wc & 1) * 64 * 8;

    // staging (slot-major): chunk c -> slot=c>>7, row=c&127; dest c*8 shorts.
    const int srow = tid & 127;     // row for both chunks
    const int ssl  = tid >> 7;      // slot 0..3 (chunk c1 = slot+4)

#define GLD(SRC, DST) __builtin_amdgcn_global_load_lds(                            \
        (const GLOBAL_AS short*)(SRC), (LDS_AS short*)(DST), 16, 0, 0)
#define STAGE_A(BUF, HALF, T) do {                                                 \
    const short* s_ = A + (size_t)(m0 + (HALF) * 128 + srow) * KDIM + (T) * 64;    \
    short* d_ = &lds[(BUF) * 32768 + (HALF) * 8192 + tid * 8];                     \
    GLD(s_ + ssl * 8, d_);  GLD(s_ + (4 + ssl) * 8, d_ + 4096);                    \
} while (0)
#define STAGE_B(BUF, HALF, T) do {                                                 \
    const short* s_ = Bm + (size_t)(n0 + (HALF) * 128 + srow) * KDIM + (T) * 64;   \
    short* d_ = &lds[(BUF) * 32768 + 16384 + (HALF) * 8192 + tid * 8];             \
    GLD(s_ + ssl * 8, d_);  GLD(s_ + (4 + ssl) * 8, d_ + 4096);                    \
} while (0)

// read A fragments: 2 Mblks (MB0, MB0+1) x 2 ksteps of k-half KH
// addr = slot*1024 + row*8 ; slot = KH*4 + ks*2 + kgrp
#define RD_A2(BUF, MB0, KH, DST) do {                                              \
    _Pragma("unroll")                                                              \
    for (int mb_ = 0; mb_ < 2; ++mb_) {                                            \
        const int row_ = ((MB0) + mb_) * 32 + arow;                                \
        _Pragma("unroll")                                                          \
        for (int ks_ = 0; ks_ < 2; ++ks_)                                          \
            DST[mb_][ks_] = *(const bf16x8*)(&lds[(BUF) * 32768 + ArdBase +        \
                ((KH) * 4 + ks_ * 2 + kgrp) * 1024 + row_ * 8]);                   \
    }                                                                              \
} while (0)
// read B fragments: 2 Nblks x 2 ksteps of k-half KH
#define RD_B2(BUF, KH, DST) do {                                                   \
    _Pragma("unroll")                                                              \
    for (int nb_ = 0; nb_ < 2; ++nb_) {                                            \
        const int row_ = nb_ * 32 + arow;                                          \
        _Pragma("unroll")                                                          \
        for (int ks_ = 0; ks_ < 2; ++ks_)                                          \
            DST[nb_][ks_] = *(const bf16x8*)(&lds[(BUF) * 32768 + BrdBase +        \
                ((KH) * 4 + ks_ * 2 + kgrp) * 1024 + row_ * 8]);                   \
    }                                                                              \
} while (0)

// quadrant: 8 MFMA of 32x32x16 -> acc[MH*2 + mb][nb]
#define MMQ(AF, BF, MH) do {                                                       \
    __builtin_amdgcn_s_setprio(1);                                                 \
    _Pragma("unroll")                                                              \
    for (int mb_ = 0; mb_ < 2; ++mb_)                                              \
        _Pragma("unroll")                                                          \
        for (int nb_ = 0; nb_ < 2; ++nb_) {                                        \
            acc[(MH)*2+mb_][nb_] = __builtin_amdgcn_mfma_f32_32x32x16_bf16(        \
                AF[mb_][0], BF[nb_][0], acc[(MH)*2+mb_][nb_], 0, 0, 0);            \
            acc[(MH)*2+mb_][nb_] = __builtin_amdgcn_mfma_f32_32x32x16_bf16(        \
                AF[mb_][1], BF[nb_][1], acc[(MH)*2+mb_][nb_], 0, 0, 0);            \
        }                                                                          \
    __builtin_amdgcn_s_setprio(0);                                                 \
} while (0)

#define BAR   __builtin_amdgcn_s_barrier()
#define VM2   asm volatile("s_waitcnt vmcnt(2)" ::: "memory")
#define VM4   asm volatile("s_waitcnt vmcnt(4)" ::: "memory")

    f32x16 acc[4][2];
    #pragma unroll
    for (int i = 0; i < 4; ++i)
        #pragma unroll
        for (int j = 0; j < 2; ++j)
            #pragma unroll
            for (int e = 0; e < 16; ++e)
                acc[i][j][e] = 0.f;

    bf16x8 afA[2][2], afB[2][2], bfA[2][2], bfB[2][2];

    // prologue: t0 full (8 loads) + t1-B (4 loads); VM4 retires t0; BAR.
    STAGE_A(0, 0, 0);  STAGE_A(0, 1, 0);  STAGE_B(0, 0, 0);  STAGE_B(0, 1, 0);
    STAGE_B(1, 0, 1);  STAGE_B(1, 1, 1);
    VM4;  BAR;
    RD_A2(0, 0, 0, afA);  RD_B2(0, 0, bfA);     // t0: Mblk0-1 kh0, B kh0

    #pragma unroll 1
    for (int it = 0; it < NIT; ++it) {
        const int ta = 2 * it + 1;                            // O (<=15)
        const int tb = (2 * it + 2 <= 15) ? 2 * it + 2 : 15;  // E2 -> buf0
        const int tc = (2 * it + 3 <= 15) ? 2 * it + 3 : 15;  // O2 -> buf1

        // p0: Q0(E)
        BAR;
        MMQ(afA, bfA, 0);
        RD_A2(0, 2, 0, afB);                 // E Mblk2-3 kh0
        STAGE_A(1, 0, ta);                   // A0(O)
        // p1: Q1(E)
        BAR;
        MMQ(afB, bfA, 1);
        RD_A2(0, 0, 1, afA);                 // E Mblk0-1 kh1
        RD_B2(0, 1, bfB);                    // E B kh1
        STAGE_A(1, 1, ta);                   // A1(O)
        // p2: Q2(E)
        BAR;
        MMQ(afA, bfB, 0);
        RD_A2(0, 2, 1, afB);                 // E Mblk2-3 kh1
        STAGE_B(0, 0, tb);                   // B0(E2)
        VM2;                                 // retires O's 8 loads
        // p3: Q3(E)  (O reads legal: secured @p2 VM2 + BAR)
        BAR;
        MMQ(afB, bfB, 1);
        RD_A2(1, 0, 0, afA);                 // O Mblk0-1 kh0
        RD_B2(1, 0, bfA);                    // O B kh0
        STAGE_B(0, 1, tb);                   // B1(E2)
        // p4: Q0(O)
        BAR;
        MMQ(afA, bfA, 0);
        RD_A2(1, 2, 0, afB);
        STAGE_A(0, 0, tb);                   // A0(E2)
        // p5: Q1(O)
        BAR;
        MMQ(afB, bfA, 1);
        RD_A2(1, 0, 1, afA);
        RD_B2(1, 1, bfB);
        STAGE_A(0, 1, tb);                   // A1(E2)
        // p6: Q2(O)
        BAR;
        MMQ(afA, bfB, 0);
        RD_A2(1, 2, 1, afB);
        STAGE_B(1, 0, tc);                   // B0(O2)
        VM2;                                 // retires E2's 8 loads
        // p7: Q3(O)  (E2 reads legal: secured @p6 VM2 + BAR)
        BAR;
        MMQ(afB, bfB, 1);
        RD_A2(0, 0, 0, afA);                 // E2 Mblk0-1 kh0
        RD_B2(0, 0, bfA);                    // E2 B kh0
        STAGE_B(1, 1, tc);                   // B1(O2)
    }

    asm volatile("s_waitcnt vmcnt(0)" ::: "memory");   // drain tail dups

    // epilogue: 32x32 C/D layout col=lane&31, row=(r&3)+8*(r>>2)+4*kgrp
    float bv2[2];
    #pragma unroll
    for (int nb = 0; nb < 2; ++nb)
        bv2[nb] = bias[n0 + wc * 64 + nb * 32 + arow];
    #pragma unroll
    for (int mb = 0; mb < 4; ++mb) {
        #pragma unroll
        for (int rg = 0; rg < 4; ++rg) {
            #pragma unroll
            for (int rr = 0; rr < 4; ++rr) {
                const int r = rg * 4 + rr;
                const size_t rowg =
                    (size_t)(m0 + wr * 128 + mb * 32 + rr + rg * 8 + 4 * kgrp) * N;
                #pragma unroll
                for (int nb = 0; nb < 2; ++nb) {
                    const int col = n0 + wc * 64 + nb * 32 + arow;
                    float v = acc[mb][nb][r] + bv2[nb];
                    if constexpr (std::is_same<OutT, float>::value) {
                        C[rowg + col] = v;
                    } else {
                        C[rowg + col] = f2b(v);
                    }
                }
            }
        }
    }
#undef GLD
#undef STAGE_A
#undef STAGE_B
#undef RD_A2
#undef RD_B2
#undef MMQ
#undef BAR
#undef VM2
#undef VM4
}

// ---------------- per-token head-mixing attention ----------------------
__global__ __launch_bounds__(256) void k_attn(
    const short* __restrict__ QKV, short* __restrict__ O)
{
    __shared__ short Ks[16][1032];
    __shared__ short Vs[16][1032];

    const int tid = threadIdx.x;
    const int tok0 = blockIdx.x * 16;

    for (int i = tid; i < 2048; i += 256) {
        int t = i >> 7;
        int j = i & 127;
        const size_t base = (size_t)(tok0 + t) * QKV_STRIDE;
        *reinterpret_cast<short8_t*>(&Ks[t][j * 8]) =
            *reinterpret_cast<const short8_t*>(&QKV[base + 1024 + j * 8]);
        *reinterpret_cast<short8_t*>(&Vs[t][j * 8]) =
            *reinterpret_cast<const short8_t*>(&QKV[base + 2048 + j * 8]);
    }
    __syncthreads();

    const int tl = tid >> 4;
    const int h  = tid & 15;

    float qf[64];
    const short* qp = QKV + (size_t)(tok0 + tl) * QKV_STRIDE + h * HD;
    #pragma unroll
    for (int i = 0; i < 8; ++i) {
        short8_t v = *reinterpret_cast<const short8_t*>(&qp[i * 8]);
        #pragma unroll
        for (int j = 0; j < 8; ++j) qf[i * 8 + j] = b2f(v[j]);
    }

    float s[16];
    #pragma unroll
    for (int g = 0; g < 16; ++g) {
        float a = 0.f;
        #pragma unroll
        for (int i = 0; i < 8; ++i) {
            short8_t kv = *reinterpret_cast<const short8_t*>(&Ks[tl][g * HD + i * 8]);
            #pragma unroll
            for (int j = 0; j < 8; ++j) a += qf[i * 8 + j] * b2f(kv[j]);
        }
        s[g] = a * 0.125f;
    }
    float mx = s[0];
    #pragma unroll
    for (int g = 1; g < 16; ++g) mx = fmaxf(mx, s[g]);
    float l = 0.f;
    #pragma unroll
    for (int g = 0; g < 16; ++g) { s[g] = __expf(s[g] - mx); l += s[g]; }
    const float inv = 1.f / l;
    #pragma unroll
    for (int g = 0; g < 16; ++g) s[g] *= inv;

    short* op = O + (size_t)(tok0 + tl) * E_DIM + h * HD;
    #pragma unroll
    for (int c = 0; c < 4; ++c) {
        float a[16];
        #pragma unroll
        for (int j = 0; j < 16; ++j) a[j] = 0.f;
        #pragma unroll
        for (int g = 0; g < 16; ++g) {
            short8_t v0 = *reinterpret_cast<const short8_t*>(&Vs[tl][g * HD + c * 16]);
            short8_t v1 = *reinterpret_cast<const short8_t*>(&Vs[tl][g * HD + c * 16 + 8]);
            #pragma unroll
            for (int j = 0; j < 8; ++j) {
                a[j]     += s[g] * b2f(v0[j]);
                a[8 + j] += s[g] * b2f(v1[j]);
            }
        }
        short8_t o0, o1;
        #pragma unroll
        for (int j = 0; j < 8; ++j) { o0[j] = f2b(a[j]); o1[j] = f2b(a[8 + j]); }
        *reinterpret_cast<short8_t*>(&op[c * 16])     = o0;
        *reinterpret_cast<short8_t*>(&op[c * 16 + 8]) = o1;
    }
}

extern "C" void kernel_launch(void* const* d_in, const int* in_sizes, int n_in,
                              void* d_out, int out_size, void* d_ws, size_t ws_size,
                              hipStream_t stream) {
    const float* x  = (const float*)d_in[0];
    const float* Wq = (const float*)d_in[1];
    const float* bq = (const float*)d_in[2];
    const float* Wk = (const float*)d_in[3];
    const float* bk = (const float*)d_in[4];
    const float* Wv = (const float*)d_in[5];
    const float* bv = (const float*)d_in[6];
    const float* Wo = (const float*)d_in[7];
    const float* bo = (const float*)d_in[8];
    float* out = (float*)d_out;

    const int T = in_sizes[0] / E_DIM;      // 32768 tokens
    char* ws = (char*)d_ws;
    const size_t SZ_X    = (size_t)T * E_DIM * 2;
    const size_t SZ_WQKV = (size_t)3 * E_DIM * E_DIM * 2;
    const size_t SZ_W    = (size_t)E_DIM * E_DIM * 2;
    const size_t SZ_B    = 3072 * sizeof(float) + 4096;

    short* xb    = (short*)(ws);
    short* Wqkvb = (short*)(ws + SZ_X);
    short* Wob   = (short*)(ws + SZ_X + SZ_WQKV);
    float* bqkv  = (float*)(ws + SZ_X + SZ_WQKV + SZ_W);
    short* QKVb  = (short*)(ws + SZ_X + SZ_WQKV + SZ_W + SZ_B);
    short* Ab    = xb;   // reuse x-bf16 buffer for attention output

    const int n4x = T * E_DIM / 4;          // 8M float4
    const int n4w = E_DIM * E_DIM / 4;      // 256K float4
    const int nprep = n4x + 4 * n4w + 768;
    k_prep<<<dim3((nprep + 255) / 256), dim3(256), 0, stream>>>(
        x, Wq, Wk, Wv, Wo, bq, bk, bv, xb, Wqkvb, Wob, bqkv, n4x, n4w);

    // fused QKV GEMM: [T][3072]
    k_gemm256<short><<<dim3((T / 256) * (QKV_STRIDE / 256)), dim3(512), 0, stream>>>(
        xb, Wqkvb, bqkv, QKVb, QKV_STRIDE / 256, QKV_STRIDE);

    k_attn<<<dim3(T / 16), dim3(256), 0, stream>>>(QKVb, Ab);

    // output GEMM: [T][1024] fp32
    k_gemm256<float><<<dim3((T / 256) * (E_DIM / 256)), dim3(512), 0, stream>>>(
        Ab, Wob, bo, out, E_DIM / 256, E_DIM);
}

// Round 19
// 386.054 us; speedup vs baseline: 1.2117x; 1.2117x over previous
//
#include <hip/hip_runtime.h>
#include <hip/hip_bf16.h>
#include <cstdint>
#include <type_traits>

#define GLOBAL_AS __attribute__((address_space(1)))
#define LDS_AS    __attribute__((address_space(3)))

typedef short bf16x8 __attribute__((ext_vector_type(8)));
typedef short short8_t __attribute__((ext_vector_type(8)));
typedef float f32x4  __attribute__((ext_vector_type(4)));

static constexpr int E_DIM = 1024;
static constexpr int HD = 64;
static constexpr int QKV_STRIDE = 3072;
static constexpr int KDIM = 1024;        // K for both GEMMs
static constexpr int NTK  = KDIM / 64;   // 16 K-tiles
static constexpr int NIT  = NTK / 2;     // 8 iterations (2 K-tiles each)

__device__ __forceinline__ float b2f(short s) {
    union { unsigned u; float f; } x;
    x.u = ((unsigned)(unsigned short)s) << 16;
    return x.f;
}
__device__ __forceinline__ short f2b(float f) {
    union { float f; unsigned u; } x; x.f = f;
    unsigned r = x.u + 0x7FFF + ((x.u >> 16) & 1);
    return (short)(r >> 16);
}

// ---- fused prep: x->bf16, Wq/Wk/Wv->Wqkvb, Wo->Wob, bias concat ----
__global__ __launch_bounds__(256) void k_prep(
    const float* __restrict__ x,
    const float* __restrict__ Wq, const float* __restrict__ Wk,
    const float* __restrict__ Wv, const float* __restrict__ Wo,
    const float* __restrict__ bq, const float* __restrict__ bk,
    const float* __restrict__ bv,
    short* __restrict__ xb, short* __restrict__ Wqkvb, short* __restrict__ Wob,
    float* __restrict__ bqkv, int n4x, int n4w)
{
    int i = blockIdx.x * 256 + threadIdx.x;
    const float* src;
    short* dst;
    int j;
    if (i < n4x)                       { src = x;  dst = xb;                  j = i; }
    else if (i < n4x + n4w)            { src = Wq; dst = Wqkvb;               j = i - n4x; }
    else if (i < n4x + 2 * n4w)        { src = Wk; dst = Wqkvb + 4 * n4w;     j = i - n4x - n4w; }
    else if (i < n4x + 3 * n4w)        { src = Wv; dst = Wqkvb + 8 * n4w;     j = i - n4x - 2 * n4w; }
    else if (i < n4x + 4 * n4w)        { src = Wo; dst = Wob;                 j = i - n4x - 3 * n4w; }
    else {
        int b = i - (n4x + 4 * n4w);
        if (b < 768) {
            #pragma unroll
            for (int e = 0; e < 4; ++e) {
                int idx = b * 4 + e;
                float v = (idx < 1024) ? bq[idx] : (idx < 2048 ? bk[idx - 1024] : bv[idx - 2048]);
                bqkv[idx] = v;
            }
        }
        return;
    }
    float4 v = reinterpret_cast<const float4*>(src)[j];
    short4 o;
    o.x = f2b(v.x); o.y = f2b(v.y); o.z = f2b(v.z); o.w = f2b(v.w);
    reinterpret_cast<short4*>(dst)[j] = o;
}

// ==== 256x256 bf16 GEMM — MFMA-first single-barrier phases (R12, best) ====
// Phase p: { BAR; MFMA on frags read at tail of p-1; issue reads for p+1;
// issue stage }. Reads pre-barrier relative to their consuming MFMA ->
// LDS drain overlaps other waves' MFMA.
// Ring (per iter, consume E=2it buf0 / O=2it+1 buf1; E2=2it+2, O2=2it+3):
//   reads: p0:bB(E) p1:af1(E) p3:af0(O)+bA(O) p4:bB(O) p5:af1(O)
//          p7:af0(E')+bA(E')   (p2,p6: none)
//   stages: p0:A1(O) p1:B0(E2) p2:B1(E2) p3:A0(E2) p4:A1(E2)
//           p5:B0(O2) p6:B1(O2) p7:A0(O2)
//   vmcnt(4) at p2/p6 tails: retires the tile consumed after the next
//   barrier ({wait->BAR->read} invariant); all staged >=2 phases before
//   first read; overwrites >=1 barrier after last read.
// Prologue: t0 full + t1{B0,B1,A0} = 14 loads; vmcnt(6) retires t0; BAR;
// read af0(t0)+bA(t0). Tail: clamped stages land in dead regions (benign).
template <typename OutT>
__global__ __launch_bounds__(512, 2) void k_gemm256(
    const short* __restrict__ A,    // [M][KDIM]
    const short* __restrict__ Bm,   // [N][KDIM]
    const float* __restrict__ bias, // [N]
    OutT* __restrict__ C,           // [M][N]
    int NT_N, int N)
{
    __shared__ short lds[65536];   // [buf]*32768 + [mat]*16384 + [half]*8192

    const int tid  = threadIdx.x;
    const int lane = tid & 63;
    const int wv   = tid >> 6;
    const int wr   = wv >> 2;       // 0..1 M half
    const int wc   = wv & 3;        // 0..3 N quarter
    const int frow = lane & 15;
    const int ks   = lane >> 4;     // k-slot within 32-k
    const int sw   = frow & 7;      // read-side swizzle key
    const int sl0  = ((0 + ks) ^ sw) * 8;   // kk=0 slot offset (shorts)
    const int sl1  = ((4 + ks) ^ sw) * 8;   // kk=1

    // bijective XCD swizzle (grid%8==0), n-fastest (neighbors share A-panel)
    const int nwg = gridDim.x, nper = nwg >> 3, bid = blockIdx.x;
    const int swz = (bid & 7) * nper + (bid >> 3);
    const int m0  = (swz / NT_N) * 256;
    const int n0  = (swz % NT_N) * 256;

    // read bases (shorts, within buf)
    const int ArdBase = wr * 8192;
    const int BrdBase = 16384 + (wc >> 1) * 8192 + (wc & 1) * 4096;

    // staging: thread covers rows srow and srow+64 of a 128-row half
    const int srow = tid >> 3;                       // 0..63
    const int ssl  = ((tid & 7) ^ (srow & 7)) * 8;   // pre-swizzled source slot
    const int sdst = tid * 8;                        // linear LDS dest

#define GLD(SRC, DST) __builtin_amdgcn_global_load_lds(                            \
        (const GLOBAL_AS short*)(SRC), (LDS_AS short*)(DST), 16, 0, 0)
#define STAGE_A(BUF, HALF, T) do {                                                 \
    const short* s_ = A + (size_t)(m0 + (HALF) * 128 + srow) * KDIM + (T) * 64 + ssl; \
    short* d_ = &lds[(BUF) * 32768 + (HALF) * 8192 + sdst];                        \
    GLD(s_, d_);  GLD(s_ + (size_t)64 * KDIM, d_ + 4096);                          \
} while (0)
#define STAGE_B(BUF, HALF, T) do {                                                 \
    const short* s_ = Bm + (size_t)(n0 + (HALF) * 128 + srow) * KDIM + (T) * 64 + ssl; \
    short* d_ = &lds[(BUF) * 32768 + 16384 + (HALF) * 8192 + sdst];                \
    GLD(s_, d_);  GLD(s_ + (size_t)64 * KDIM, d_ + 4096);                          \
} while (0)

#define RD_A(BUF, MIB) do {                                                        \
    _Pragma("unroll")                                                              \
    for (int m_ = 0; m_ < 4; ++m_) {                                               \
        const short* p_ = &lds[(BUF) * 32768 + ArdBase + ((MIB) + m_) * 1024 + frow * 64]; \
        af[m_][0] = *(const bf16x8*)(p_ + sl0);                                    \
        af[m_][1] = *(const bf16x8*)(p_ + sl1);                                    \
    }                                                                              \
} while (0)
#define RD_B(BUF, NIB, BF) do {                                                    \
    _Pragma("unroll")                                                              \
    for (int n_ = 0; n_ < 2; ++n_) {                                               \
        const short* p_ = &lds[(BUF) * 32768 + BrdBase + ((NIB) + n_) * 1024 + frow * 64]; \
        BF[n_][0] = *(const bf16x8*)(p_ + sl0);                                    \
        BF[n_][1] = *(const bf16x8*)(p_ + sl1);                                    \
    }                                                                              \
} while (0)

#define MM(MB, NB, BF) do {                                                        \
    __builtin_amdgcn_s_setprio(1);                                                 \
    _Pragma("unroll")                                                              \
    for (int m_ = 0; m_ < 4; ++m_)                                                 \
        _Pragma("unroll")                                                          \
        for (int n_ = 0; n_ < 2; ++n_) {                                           \
            acc[(MB)+m_][(NB)+n_] = __builtin_amdgcn_mfma_f32_16x16x32_bf16(       \
                af[m_][0], BF[n_][0], acc[(MB)+m_][(NB)+n_], 0, 0, 0);             \
            acc[(MB)+m_][(NB)+n_] = __builtin_amdgcn_mfma_f32_16x16x32_bf16(       \
                af[m_][1], BF[n_][1], acc[(MB)+m_][(NB)+n_], 0, 0, 0);             \
        }                                                                          \
    __builtin_amdgcn_s_setprio(0);                                                 \
} while (0)

#define BAR   __builtin_amdgcn_s_barrier()
#define VM4   asm volatile("s_waitcnt vmcnt(4)" ::: "memory")
#define VM6   asm volatile("s_waitcnt vmcnt(6)" ::: "memory")

    f32x4 acc[8][4];
    #pragma unroll
    for (int i = 0; i < 8; ++i)
        #pragma unroll
        for (int j = 0; j < 4; ++j)
            acc[i][j] = (f32x4){0.f, 0.f, 0.f, 0.f};

    bf16x8 af[4][2], bfA[2][2], bfB[2][2];

    // prologue: t0 full (8) + t1 {B0,B1,A0} (6); VM6 retires t0; BAR; Q0 reads.
    STAGE_B(0, 0, 0);  STAGE_B(0, 1, 0);
    STAGE_A(0, 0, 0);  STAGE_A(0, 1, 0);
    STAGE_B(1, 0, 1);  STAGE_B(1, 1, 1);
    STAGE_A(1, 0, 1);
    VM6;  BAR;
    RD_A(0, 0);  RD_B(0, 0, bfA);        // af0(t0), bA(t0) — pre-BAR(p0)

    #pragma unroll 1
    for (int it = 0; it < NIT; ++it) {
        const int ta = 2 * it + 1;                            // <=15 always
        const int tb = (2 * it + 2 <= 15) ? 2 * it + 2 : 15;  // E2 (buf0)
        const int tc = (2 * it + 3 <= 15) ? 2 * it + 3 : 15;  // O2 (buf1)

        // p0: Q0(E)
        BAR;
        MM(0, 0, bfA);
        RD_B(0, 2, bfB);                 // bB(E)
        STAGE_A(1, 1, ta);               // A1(O)
        // p1: Q1(E)
        BAR;
        MM(0, 2, bfB);
        RD_A(0, 4);                      // af1(E)
        STAGE_B(0, 0, tb);               // B0(E2)
        // p2: Q2(E)
        BAR;
        MM(4, 0, bfA);
        STAGE_B(0, 1, tb);               // B1(E2)
        VM4;                             // O fully resident before p3-reads
        // p3: Q3(E)
        BAR;
        MM(4, 2, bfB);
        RD_A(1, 0);  RD_B(1, 0, bfA);    // af0(O), bA(O)
        STAGE_A(0, 0, tb);               // A0(E2)
        // p4: Q0(O)
        BAR;
        MM(0, 0, bfA);
        RD_B(1, 2, bfB);                 // bB(O)
        STAGE_A(0, 1, tb);               // A1(E2)
        // p5: Q1(O)
        BAR;
        MM(0, 2, bfB);
        RD_A(1, 4);                      // af1(O)
        STAGE_B(1, 0, tc);               // B0(O2)
        // p6: Q2(O)
        BAR;
        MM(4, 0, bfA);
        STAGE_B(1, 1, tc);               // B1(O2)
        VM4;                             // E2 fully resident before p7-reads
        // p7: Q3(O)
        BAR;
        MM(4, 2, bfB);
        RD_A(0, 0);  RD_B(0, 0, bfA);    // af0(E'), bA(E') — next iter's Q0
        STAGE_A(1, 0, tc);               // A0(O2)
    }

    asm volatile("s_waitcnt vmcnt(0)" ::: "memory");   // drain tail dups

    // epilogue: C/D layout col = lane&15, row = (lane>>4)*4 + r
    const int crow = (lane >> 4) * 4;
    const int ccol = lane & 15;
    float bv4[4];
    #pragma unroll
    for (int ni = 0; ni < 4; ++ni)
        bv4[ni] = bias[n0 + wc * 64 + ni * 16 + ccol];
    #pragma unroll
    for (int mi = 0; mi < 8; ++mi) {
        #pragma unroll
        for (int r = 0; r < 4; ++r) {
            const size_t rowg = (size_t)(m0 + wr * 128 + mi * 16 + crow + r) * N;
            #pragma unroll
            for (int ni = 0; ni < 4; ++ni) {
                const int col = n0 + wc * 64 + ni * 16 + ccol;
                float v = acc[mi][ni][r] + bv4[ni];
                if constexpr (std::is_same<OutT, float>::value) {
                    C[rowg + col] = v;
                } else {
                    C[rowg + col] = f2b(v);
                }
            }
        }
    }
#undef GLD
#undef STAGE_A
#undef STAGE_B
#undef RD_A
#undef RD_B
#undef MM
#undef BAR
#undef VM4
#undef VM6
}

// ---------------- per-token head-mixing attention ----------------------
__global__ __launch_bounds__(256) void k_attn(
    const short* __restrict__ QKV, short* __restrict__ O)
{
    __shared__ short Ks[16][1032];
    __shared__ short Vs[16][1032];

    const int tid = threadIdx.x;
    const int tok0 = blockIdx.x * 16;

    for (int i = tid; i < 2048; i += 256) {
        int t = i >> 7;
        int j = i & 127;
        const size_t base = (size_t)(tok0 + t) * QKV_STRIDE;
        *reinterpret_cast<short8_t*>(&Ks[t][j * 8]) =
            *reinterpret_cast<const short8_t*>(&QKV[base + 1024 + j * 8]);
        *reinterpret_cast<short8_t*>(&Vs[t][j * 8]) =
            *reinterpret_cast<const short8_t*>(&QKV[base + 2048 + j * 8]);
    }
    __syncthreads();

    const int tl = tid >> 4;
    const int h  = tid & 15;

    float qf[64];
    const short* qp = QKV + (size_t)(tok0 + tl) * QKV_STRIDE + h * HD;
    #pragma unroll
    for (int i = 0; i < 8; ++i) {
        short8_t v = *reinterpret_cast<const short8_t*>(&qp[i * 8]);
        #pragma unroll
        for (int j = 0; j < 8; ++j) qf[i * 8 + j] = b2f(v[j]);
    }

    float s[16];
    #pragma unroll
    for (int g = 0; g < 16; ++g) {
        float a = 0.f;
        #pragma unroll
        for (int i = 0; i < 8; ++i) {
            short8_t kv = *reinterpret_cast<const short8_t*>(&Ks[tl][g * HD + i * 8]);
            #pragma unroll
            for (int j = 0; j < 8; ++j) a += qf[i * 8 + j] * b2f(kv[j]);
        }
        s[g] = a * 0.125f;
    }
    float mx = s[0];
    #pragma unroll
    for (int g = 1; g < 16; ++g) mx = fmaxf(mx, s[g]);
    float l = 0.f;
    #pragma unroll
    for (int g = 0; g < 16; ++g) { s[g] = __expf(s[g] - mx); l += s[g]; }
    const float inv = 1.f / l;
    #pragma unroll
    for (int g = 0; g < 16; ++g) s[g] *= inv;

    short* op = O + (size_t)(tok0 + tl) * E_DIM + h * HD;
    #pragma unroll
    for (int c = 0; c < 4; ++c) {
        float a[16];
        #pragma unroll
        for (int j = 0; j < 16; ++j) a[j] = 0.f;
        #pragma unroll
        for (int g = 0; g < 16; ++g) {
            short8_t v0 = *reinterpret_cast<const short8_t*>(&Vs[tl][g * HD + c * 16]);
            short8_t v1 = *reinterpret_cast<const short8_t*>(&Vs[tl][g * HD + c * 16 + 8]);
            #pragma unroll
            for (int j = 0; j < 8; ++j) {
                a[j]     += s[g] * b2f(v0[j]);
                a[8 + j] += s[g] * b2f(v1[j]);
            }
        }
        short8_t o0, o1;
        #pragma unroll
        for (int j = 0; j < 8; ++j) { o0[j] = f2b(a[j]); o1[j] = f2b(a[8 + j]); }
        *reinterpret_cast<short8_t*>(&op[c * 16])     = o0;
        *reinterpret_cast<short8_t*>(&op[c * 16 + 8]) = o1;
    }
}

extern "C" void kernel_launch(void* const* d_in, const int* in_sizes, int n_in,
                              void* d_out, int out_size, void* d_ws, size_t ws_size,
                              hipStream_t stream) {
    const float* x  = (const float*)d_in[0];
    const float* Wq = (const float*)d_in[1];
    const float* bq = (const float*)d_in[2];
    const float* Wk = (const float*)d_in[3];
    const float* bk = (const float*)d_in[4];
    const float* Wv = (const float*)d_in[5];
    const float* bv = (const float*)d_in[6];
    const float* Wo = (const float*)d_in[7];
    const float* bo = (const float*)d_in[8];
    float* out = (float*)d_out;

    const int T = in_sizes[0] / E_DIM;      // 32768 tokens
    char* ws = (char*)d_ws;
    const size_t SZ_X    = (size_t)T * E_DIM * 2;
    const size_t SZ_WQKV = (size_t)3 * E_DIM * E_DIM * 2;
    const size_t SZ_W    = (size_t)E_DIM * E_DIM * 2;
    const size_t SZ_B    = 3072 * sizeof(float) + 4096;

    short* xb    = (short*)(ws);
    short* Wqkvb = (short*)(ws + SZ_X);
    short* Wob   = (short*)(ws + SZ_X + SZ_WQKV);
    float* bqkv  = (float*)(ws + SZ_X + SZ_WQKV + SZ_W);
    short* QKVb  = (short*)(ws + SZ_X + SZ_WQKV + SZ_W + SZ_B);
    short* Ab    = xb;   // reuse x-bf16 buffer for attention output

    const int n4x = T * E_DIM / 4;          // 8M float4
    const int n4w = E_DIM * E_DIM / 4;      // 256K float4
    const int nprep = n4x + 4 * n4w + 768;
    k_prep<<<dim3((nprep + 255) / 256), dim3(256), 0, stream>>>(
        x, Wq, Wk, Wv, Wo, bq, bk, bv, xb, Wqkvb, Wob, bqkv, n4x, n4w);

    // fused QKV GEMM: [T][3072]
    k_gemm256<short><<<dim3((T / 256) * (QKV_STRIDE / 256)), dim3(512), 0, stream>>>(
        xb, Wqkvb, bqkv, QKVb, QKV_STRIDE / 256, QKV_STRIDE);

    k_attn<<<dim3(T / 16), dim3(256), 0, stream>>>(QKVb, Ab);

    // output GEMM: [T][1024] fp32
    k_gemm256<float><<<dim3((T / 256) * (E_DIM / 256)), dim3(512), 0, stream>>>(
        Ab, Wob, bo, out, E_DIM / 256, E_DIM);
}